// Round 1
// baseline (28122.089 us; speedup 1.0000x reference)
//
#include <hip/hip_runtime.h>
#include <math.h>

#define DIM 64
#define NFEAT 14
#define EFEAT 4
#define ODIM 16
#define NGRAPH 512
#define NEG 0.01f

__device__ __forceinline__ float leaky(float v){ return v >= 0.f ? v : NEG*v; }
__device__ __forceinline__ float sigm(float v){ return 1.f/(1.f+expf(-v)); }

// ---------------- small prep kernels ----------------

__global__ void k_transpose(const float* __restrict__ wih, const float* __restrict__ whh,
                            float* __restrict__ wihT, float* __restrict__ whhT){
    int i = blockIdx.x*blockDim.x + threadIdx.x;
    if (i < 192*64){ int j = i/64, d = i%64; wihT[d*192+j] = wih[i]; }
    else if (i < 2*192*64){ int t = i - 192*64; int j = t/64, d = t%64; whhT[d*192+j] = whh[t]; }
}

__global__ void k_hid(const float* __restrict__ ea, const float* __restrict__ w1,
                      const float* __restrict__ b1, float* __restrict__ hid, int E){
    int i = blockIdx.x*blockDim.x + threadIdx.x;
    if (i >= E*DIM) return;
    int e = i >> 6, k = i & 63;
    const float* a = ea + (size_t)e*EFEAT;
    const float* w = w1 + k*EFEAT;
    float v = b1[k] + a[0]*w[0] + a[1]*w[1] + a[2]*w[2] + a[3]*w[3];
    hid[i] = leaky(v);
}

__global__ void k_deg(const int* __restrict__ ei, float* __restrict__ deg, int E){
    int e = blockIdx.x*blockDim.x + threadIdx.x;
    if (e < E) atomicAdd(&deg[ei[E + e]], 1.0f);
}

__global__ void k_invdeg(float* __restrict__ deg, int N){
    int i = blockIdx.x*blockDim.x + threadIdx.x;
    if (i < N) deg[i] = 1.0f / fmaxf(deg[i], 1.0f);
}

__global__ void k_lin0(const float* __restrict__ x, const float* __restrict__ w,
                       const float* __restrict__ b, float* __restrict__ out,
                       float* __restrict__ h, int N){
    int i = blockIdx.x*blockDim.x + threadIdx.x;
    if (i >= N*DIM) return;
    int n = i >> 6, o = i & 63;
    const float* xr = x + (size_t)n*NFEAT;
    const float* wr = w + o*NFEAT;
    float v = b[o];
#pragma unroll
    for (int f = 0; f < NFEAT; ++f) v += xr[f]*wr[f];
    v = leaky(v);
    out[i] = v; h[i] = v;
}

// ---------------- ew = hid @ w2^T + b2  (E x 4096) ----------------
__global__ __launch_bounds__(256) void k_ew(const float* __restrict__ hid,
                                            const float* __restrict__ w2,
                                            const float* __restrict__ b2,
                                            float* __restrict__ ew, int E){
    __shared__ float As[64][64];
    __shared__ float Bs[64][65];
    int brow = blockIdx.x, bcol = blockIdx.y;
    int tid = threadIdx.x;
    int tx = tid & 15, ty = tid >> 4;
    int row0 = brow*64;
    for (int i = tid; i < 64*64; i += 256){
        int m = i >> 6, k = i & 63;
        int e = row0 + m;
        As[m][k] = (e < E) ? hid[(size_t)e*64 + k] : 0.f;
    }
    for (int i = tid; i < 64*64; i += 256){
        int j = i >> 6, k = i & 63;
        Bs[k][j] = w2[((size_t)(bcol*64 + j))*64 + k];
    }
    __syncthreads();
    float acc[4][4] = {};
#pragma unroll 8
    for (int k = 0; k < 64; ++k){
        float a0 = As[ty*4+0][k], a1 = As[ty*4+1][k], a2 = As[ty*4+2][k], a3 = As[ty*4+3][k];
        float b0 = Bs[k][tx*4+0], b1v = Bs[k][tx*4+1], b2v = Bs[k][tx*4+2], b3v = Bs[k][tx*4+3];
        acc[0][0] += a0*b0; acc[0][1] += a0*b1v; acc[0][2] += a0*b2v; acc[0][3] += a0*b3v;
        acc[1][0] += a1*b0; acc[1][1] += a1*b1v; acc[1][2] += a1*b2v; acc[1][3] += a1*b3v;
        acc[2][0] += a2*b0; acc[2][1] += a2*b1v; acc[2][2] += a2*b2v; acc[2][3] += a2*b3v;
        acc[3][0] += a3*b0; acc[3][1] += a3*b1v; acc[3][2] += a3*b2v; acc[3][3] += a3*b3v;
    }
#pragma unroll
    for (int i = 0; i < 4; ++i){
        int e = row0 + ty*4 + i;
        if (e >= E) continue;
        size_t base = (size_t)e*4096 + bcol*64 + tx*4;
        int cb = bcol*64 + tx*4;
#pragma unroll
        for (int j = 0; j < 4; ++j) ew[base + j] = acc[i][j] + b2[cb + j];
    }
}

// ---------------- per-iteration: message + scatter ----------------
__global__ __launch_bounds__(256) void k_msg(const float* __restrict__ out,
                                             const float* __restrict__ ew,
                                             const int* __restrict__ ei,
                                             float* __restrict__ agg, int E){
    int gw = (blockIdx.x*blockDim.x + threadIdx.x) >> 6;  // one wave per edge
    int o = threadIdx.x & 63;
    if (gw >= E) return;
    int src = ei[gw], tgt = ei[E + gw];
    float srcv = out[(size_t)src*64 + o];
    const float* ewr = ew + (size_t)gw*4096;
    float acc = 0.f;
#pragma unroll
    for (int d = 0; d < 64; d += 4){
        float s0 = __shfl(srcv, d,   64);
        float s1 = __shfl(srcv, d+1, 64);
        float s2 = __shfl(srcv, d+2, 64);
        float s3 = __shfl(srcv, d+3, 64);
        acc += s0*ewr[d*64+o] + s1*ewr[(d+1)*64+o] + s2*ewr[(d+2)*64+o] + s3*ewr[(d+3)*64+o];
    }
    atomicAdd(&agg[(size_t)tgt*64 + o], acc);
}

// fallback: recompute ew on the fly (used only if d_ws too small)
__global__ __launch_bounds__(256) void k_msg_otf(const float* __restrict__ out,
                                                 const float* __restrict__ hid,
                                                 const float* __restrict__ w2,
                                                 const float* __restrict__ b2,
                                                 const int* __restrict__ ei,
                                                 float* __restrict__ agg, int E){
    __shared__ float sh[4][64];
    int wl = threadIdx.x >> 6;
    int o  = threadIdx.x & 63;
    int e  = blockIdx.x*4 + wl;
    bool valid = e < E;
    if (valid) sh[wl][o] = hid[(size_t)e*64 + o];
    if (!valid) return;
    int src = ei[e], tgt = ei[E + e];
    float srcv = out[(size_t)src*64 + o];
    float msg = 0.f;
    for (int d = 0; d < 64; ++d){
        const float* wr = w2 + ((size_t)(d*64 + o))*64;
        float ewdo = b2[d*64 + o];
#pragma unroll 8
        for (int k = 0; k < 64; ++k) ewdo += sh[wl][k]*wr[k];
        msg += __shfl(srcv, d, 64) * ewdo;
    }
    atomicAdd(&agg[(size_t)tgt*64 + o], msg);
}

// ---------------- per-iteration: conv + GRU node update ----------------
__global__ __launch_bounds__(256) void k_node(float* __restrict__ out, float* __restrict__ h,
                                              const float* __restrict__ agg,
                                              const float* __restrict__ invdeg,
                                              const float* __restrict__ rootw,
                                              const float* __restrict__ convb,
                                              const float* __restrict__ wihT,
                                              const float* __restrict__ whhT,
                                              const float* __restrict__ bih,
                                              const float* __restrict__ bhh, int N){
    int gw = (blockIdx.x*blockDim.x + threadIdx.x) >> 6;  // one wave per node
    int o = threadIdx.x & 63;
    if (gw >= N) return;
    size_t base = (size_t)gw*64;
    float outv = out[base + o];
    float hv   = h[base + o];
    float conv = agg[base + o]*invdeg[gw] + convb[o];
#pragma unroll 4
    for (int d = 0; d < 64; ++d) conv += __shfl(outv, d, 64) * rootw[d*64 + o];
    float m = leaky(conv);
    float gir = bih[o], giz = bih[64+o], gin = bih[128+o];
    float ghr = bhh[o], ghz = bhh[64+o], ghn = bhh[128+o];
#pragma unroll 4
    for (int d = 0; d < 64; ++d){
        float md = __shfl(m, d, 64);
        float hd = __shfl(hv, d, 64);
        const float* wi = wihT + d*192;
        const float* wh = whhT + d*192;
        gir += md*wi[o]; giz += md*wi[64+o]; gin += md*wi[128+o];
        ghr += hd*wh[o]; ghz += hd*wh[64+o]; ghn += hd*wh[128+o];
    }
    float r = sigm(gir + ghr), z = sigm(giz + ghz);
    float nn = tanhf(gin + r*ghn);
    float hnew = (1.f - z)*nn + z*hv;
    h[base + o] = hnew;
    out[base + o] = hnew;
}

// ---------------- Set2Set (1 step, zero init) + readout ----------------
__global__ void k_q(const float* __restrict__ bih, const float* __restrict__ bhh,
                    float* __restrict__ q){
    int j = threadIdx.x;
    if (j >= 64) return;
    float gi = bih[j]       + bhh[j];
    float gf = bih[64+j]    + bhh[64+j];   (void)gf; // f gate * c(=0) contributes nothing
    float gg = bih[128+j]   + bhh[128+j];
    float go = bih[192+j]   + bhh[192+j];
    float c = sigm(gi)*tanhf(gg);
    q[j] = sigm(go)*tanhf(c);
}

__device__ __forceinline__ unsigned fkey(float f){
    unsigned u = __float_as_uint(f);
    return (u >> 31) ? ~u : (u | 0x80000000u);
}

__global__ void k_edot(const float* __restrict__ out, const float* __restrict__ q,
                       const int* __restrict__ batch, float* __restrict__ ebuf,
                       unsigned* __restrict__ emaxk, int N){
    int gw = (blockIdx.x*blockDim.x + threadIdx.x) >> 6;
    int d = threadIdx.x & 63;
    if (gw >= N) return;
    float v = out[(size_t)gw*64 + d] * q[d];
#pragma unroll
    for (int s = 32; s; s >>= 1) v += __shfl_xor(v, s, 64);
    if (d == 0){
        ebuf[gw] = v;
        atomicMax(&emaxk[batch[gw]], fkey(v));
    }
}

__global__ void k_ex(float* __restrict__ ebuf, const unsigned* __restrict__ emaxk,
                     const int* __restrict__ batch, float* __restrict__ denom, int N){
    int n = blockIdx.x*blockDim.x + threadIdx.x;
    if (n >= N) return;
    int b = batch[n];
    unsigned k = emaxk[b];
    float em = (k == 0u) ? 0.f
             : ((k >> 31) ? __uint_as_float(k ^ 0x80000000u) : __uint_as_float(~k));
    float ex = expf(ebuf[n] - em);
    ebuf[n] = ex;
    atomicAdd(&denom[b], ex);
}

__global__ void k_rr(const float* __restrict__ out, const float* __restrict__ ebuf,
                     const float* __restrict__ denom, const int* __restrict__ batch,
                     float* __restrict__ rr, int N){
    int gw = (blockIdx.x*blockDim.x + threadIdx.x) >> 6;
    int o = threadIdx.x & 63;
    if (gw >= N) return;
    int b = batch[gw];
    float a = ebuf[gw] / fmaxf(denom[b], 1e-16f);
    atomicAdd(&rr[(size_t)b*64 + o], a * out[(size_t)gw*64 + o]);
}

__global__ void k_out(const float* __restrict__ q, const float* __restrict__ rr,
                      const float* __restrict__ lw, const float* __restrict__ lb,
                      float* __restrict__ dout){
    int i = blockIdx.x*blockDim.x + threadIdx.x;
    if (i >= NGRAPH*ODIM) return;
    int b = i / ODIM, j = i % ODIM;
    const float* w = lw + j*128;
    float acc = lb[j];
#pragma unroll 8
    for (int d = 0; d < 64; ++d) acc += w[d]*q[d];
    const float* rb = rr + (size_t)b*64;
#pragma unroll 8
    for (int d = 0; d < 64; ++d) acc += w[64+d]*rb[d];
    dout[i] = acc;
}

// ---------------- launch ----------------
extern "C" void kernel_launch(void* const* d_in, const int* in_sizes, int n_in,
                              void* d_out, int out_size, void* d_ws, size_t ws_size,
                              hipStream_t stream){
    const float* x     = (const float*)d_in[0];
    const float* ea    = (const float*)d_in[1];
    const int*   ei    = (const int*)  d_in[2];
    const int*   batch = (const int*)  d_in[3];
    const float* lin0w = (const float*)d_in[4];
    const float* lin0b = (const float*)d_in[5];
    const float* w1    = (const float*)d_in[6];
    const float* b1    = (const float*)d_in[7];
    const float* w2    = (const float*)d_in[8];
    const float* b2    = (const float*)d_in[9];
    const float* rootw = (const float*)d_in[10];
    const float* convb = (const float*)d_in[11];
    const float* gwih  = (const float*)d_in[12];
    const float* gwhh  = (const float*)d_in[13];
    const float* gbih  = (const float*)d_in[14];
    const float* gbhh  = (const float*)d_in[15];
    const float* lsbih = (const float*)d_in[18];
    const float* lsbhh = (const float*)d_in[19];
    const float* loutw = (const float*)d_in[20];
    const float* loutb = (const float*)d_in[21];

    int N = in_sizes[0] / NFEAT;
    int E = in_sizes[1] / EFEAT;

    char* p = (char*)d_ws;
    size_t off = 0;
    auto carve = [&](size_t bytes) -> void* {
        void* r = p + off;
        off += (bytes + 255) & ~(size_t)255;
        return r;
    };
    float*    hid    = (float*)   carve((size_t)E*64*4);
    float*    outb   = (float*)   carve((size_t)N*64*4);
    float*    hb     = (float*)   carve((size_t)N*64*4);
    float*    agg    = (float*)   carve((size_t)N*64*4);
    float*    invdeg = (float*)   carve((size_t)N*4);
    float*    qv     = (float*)   carve(64*4);
    float*    ebuf   = (float*)   carve((size_t)N*4);
    unsigned* emaxk  = (unsigned*)carve(NGRAPH*4);
    float*    denom  = (float*)   carve(NGRAPH*4);
    float*    rr     = (float*)   carve((size_t)NGRAPH*64*4);
    float*    wihT   = (float*)   carve(192*64*4);
    float*    whhT   = (float*)   carve(192*64*4);
    float*    ew     = (float*)(p + off);
    size_t need_ew = off + (size_t)E*4096*4;
    bool use_ew = (ws_size >= need_ew);

    // zero accumulators used this call
    hipMemsetAsync(invdeg, 0, (size_t)N*4, stream);
    hipMemsetAsync(emaxk, 0, NGRAPH*4, stream);
    hipMemsetAsync(denom, 0, NGRAPH*4, stream);
    hipMemsetAsync(rr,    0, (size_t)NGRAPH*64*4, stream);

    k_transpose<<<(2*192*64 + 255)/256, 256, 0, stream>>>(gwih, gwhh, wihT, whhT);
    k_hid<<<((size_t)E*64 + 255)/256, 256, 0, stream>>>(ea, w1, b1, hid, E);
    k_deg<<<(E + 255)/256, 256, 0, stream>>>(ei, invdeg, E);
    k_invdeg<<<(N + 255)/256, 256, 0, stream>>>(invdeg, N);
    k_lin0<<<((size_t)N*64 + 255)/256, 256, 0, stream>>>(x, lin0w, lin0b, outb, hb, N);

    if (use_ew){
        dim3 g((E + 63)/64, 64);
        k_ew<<<g, 256, 0, stream>>>(hid, w2, b2, ew, E);
    }

    int msg_grid  = ((size_t)E*64 + 255)/256;
    int node_grid = ((size_t)N*64 + 255)/256;
    for (int it = 0; it < 6; ++it){
        hipMemsetAsync(agg, 0, (size_t)N*64*4, stream);
        if (use_ew)
            k_msg<<<msg_grid, 256, 0, stream>>>(outb, ew, ei, agg, E);
        else
            k_msg_otf<<<(E + 3)/4, 256, 0, stream>>>(outb, hid, w2, b2, ei, agg, E);
        k_node<<<node_grid, 256, 0, stream>>>(outb, hb, agg, invdeg, rootw, convb,
                                              wihT, whhT, gbih, gbhh, N);
    }

    k_q<<<1, 64, 0, stream>>>(lsbih, lsbhh, qv);
    k_edot<<<node_grid, 256, 0, stream>>>(outb, qv, batch, ebuf, emaxk, N);
    k_ex<<<(N + 255)/256, 256, 0, stream>>>(ebuf, emaxk, batch, denom, N);
    k_rr<<<node_grid, 256, 0, stream>>>(outb, ebuf, denom, batch, rr, N);
    k_out<<<(NGRAPH*ODIM + 255)/256, 256, 0, stream>>>(qv, rr, loutw, loutb, (float*)d_out);
}

// Round 2
// 2901.083 us; speedup vs baseline: 9.6937x; 9.6937x over previous
//
#include <hip/hip_runtime.h>
#include <math.h>

#define DIM 64
#define NFEAT 14
#define EFEAT 4
#define ODIM 16
#define NGRAPH 512
#define NEG 0.01f

__device__ __forceinline__ float leaky(float v){ return v >= 0.f ? v : NEG*v; }
__device__ __forceinline__ float sigm(float v){ return 1.f/(1.f+expf(-v)); }

// ---------------- small prep kernels ----------------

__global__ void k_transpose(const float* __restrict__ wih, const float* __restrict__ whh,
                            float* __restrict__ wihT, float* __restrict__ whhT){
    int i = blockIdx.x*blockDim.x + threadIdx.x;
    if (i < 192*64){ int j = i/64, d = i%64; wihT[d*192+j] = wih[i]; }
    else if (i < 2*192*64){ int t = i - 192*64; int j = t/64, d = t%64; whhT[d*192+j] = whh[t]; }
}

// Wperm[(d*64+k)*64+o] = W2[(d*64+o)*64+k]
__global__ void k_wperm(const float* __restrict__ w2, float* __restrict__ wp){
    int i = blockIdx.x*blockDim.x + threadIdx.x;
    if (i >= 64*64*64) return;
    int o = i & 63, k = (i >> 6) & 63, d = i >> 12;
    wp[i] = w2[((size_t)(d*64 + o))*64 + k];
}

__global__ void k_hid(const float* __restrict__ ea, const float* __restrict__ w1,
                      const float* __restrict__ b1, float* __restrict__ hid, int E){
    int i = blockIdx.x*blockDim.x + threadIdx.x;
    if (i >= E*DIM) return;
    int e = i >> 6, k = i & 63;
    const float* a = ea + (size_t)e*EFEAT;
    const float* w = w1 + k*EFEAT;
    float v = b1[k] + a[0]*w[0] + a[1]*w[1] + a[2]*w[2] + a[3]*w[3];
    hid[i] = leaky(v);
}

__global__ void k_deg(const int* __restrict__ ei, float* __restrict__ deg, int E){
    int e = blockIdx.x*blockDim.x + threadIdx.x;
    if (e < E) atomicAdd(&deg[ei[E + e]], 1.0f);
}

__global__ void k_invdeg(float* __restrict__ deg, int N){
    int i = blockIdx.x*blockDim.x + threadIdx.x;
    if (i < N) deg[i] = 1.0f / fmaxf(deg[i], 1.0f);
}

__global__ void k_lin0(const float* __restrict__ x, const float* __restrict__ w,
                       const float* __restrict__ b, float* __restrict__ out,
                       float* __restrict__ h, int N){
    int i = blockIdx.x*blockDim.x + threadIdx.x;
    if (i >= N*DIM) return;
    int n = i >> 6, o = i & 63;
    const float* xr = x + (size_t)n*NFEAT;
    const float* wr = w + o*NFEAT;
    float v = b[o];
#pragma unroll
    for (int f = 0; f < NFEAT; ++f) v += xr[f]*wr[f];
    v = leaky(v);
    out[i] = v; h[i] = v;
}

// ---------------- fused message GEMM + scatter ----------------
// Per block: 64 edges. msg[e,o] = sum_d out[src_e,d] * ( sum_k hid[e,k]*Wperm[(d*64+k)*64+o] )
//                               + sum_d out[src_e,d] * b2[d*64+o]
__global__ __launch_bounds__(256) void k_fmsg(const float* __restrict__ out,
                                              const float* __restrict__ hid,
                                              const float* __restrict__ wperm,
                                              const float* __restrict__ b2,
                                              const int* __restrict__ ei,
                                              float* __restrict__ agg, int E){
    __shared__ float Os[64][65];      // out[src_e][d]
    __shared__ float Hs[64][68];      // hid transposed: Hs[k][e]
    __shared__ float Ws[2][64][64];   // two d-slices of Wperm (or b2 tile)
    __shared__ int   ssrc[64];
    __shared__ int   stgt[64];
    int tid = threadIdx.x;
    int e0 = blockIdx.x * 64;
    if (tid < 64){
        int e = e0 + tid;
        ssrc[tid] = (e < E) ? ei[e] : -1;
        stgt[tid] = (e < E) ? ei[E + e] : -1;
    }
    __syncthreads();
    for (int i = tid; i < 4096; i += 256){
        int e = i >> 6, d = i & 63;
        int s = ssrc[e];
        Os[e][d] = (s >= 0) ? out[(size_t)s*64 + d] : 0.f;
    }
    for (int i = tid; i < 4096; i += 256){
        int e = i >> 6, k = i & 63;
        Hs[k][e] = (ssrc[e] >= 0) ? hid[(size_t)(e0 + e)*64 + k] : 0.f;
    }

    int tx = tid & 15, ty = tid >> 4;
    int r0 = ty*4, c0 = tx*4;
    float acc[4][4] = {{0.f}};

    for (int g = 0; g < 32; ++g){
        __syncthreads();   // also covers Os/Hs staging at g=0
        const float4* wsrc = (const float4*)(wperm + (size_t)g*8192);
        float4* wdst = (float4*)Ws;
        for (int i = tid; i < 2048; i += 256) wdst[i] = wsrc[i];
        __syncthreads();

        float p0[4][4] = {{0.f}}, p1[4][4] = {{0.f}};
#pragma unroll 4
        for (int k = 0; k < 64; ++k){
            float4 a  = *(const float4*)&Hs[k][r0];
            float4 b0 = *(const float4*)&Ws[0][k][c0];
            float4 b1 = *(const float4*)&Ws[1][k][c0];
            float av[4] = {a.x, a.y, a.z, a.w};
            float b0v[4] = {b0.x, b0.y, b0.z, b0.w};
            float b1v[4] = {b1.x, b1.y, b1.z, b1.w};
#pragma unroll
            for (int i = 0; i < 4; ++i)
#pragma unroll
                for (int j = 0; j < 4; ++j){
                    p0[i][j] += av[i]*b0v[j];
                    p1[i][j] += av[i]*b1v[j];
                }
        }
        int d0 = 2*g, d1 = d0 + 1;
#pragma unroll
        for (int i = 0; i < 4; ++i){
            float oa = Os[r0 + i][d0];
            float ob = Os[r0 + i][d1];
#pragma unroll
            for (int j = 0; j < 4; ++j)
                acc[i][j] += oa*p0[i][j] + ob*p1[i][j];
        }
    }

    // bias pass: b2 is already [64d][64o] row-major
    __syncthreads();
    {
        const float4* bsrc = (const float4*)b2;
        float4* bdst = (float4*)Ws[0];
        for (int i = tid; i < 1024; i += 256) bdst[i] = bsrc[i];
    }
    __syncthreads();
#pragma unroll 8
    for (int d = 0; d < 64; ++d){
        float4 b = *(const float4*)&Ws[0][d][c0];
        float bv[4] = {b.x, b.y, b.z, b.w};
#pragma unroll
        for (int i = 0; i < 4; ++i){
            float oa = Os[r0 + i][d];
#pragma unroll
            for (int j = 0; j < 4; ++j) acc[i][j] += oa*bv[j];
        }
    }

    // scatter
#pragma unroll
    for (int i = 0; i < 4; ++i){
        int t = stgt[r0 + i];
        if (t < 0) continue;
        float* ap = agg + (size_t)t*64 + c0;
#pragma unroll
        for (int j = 0; j < 4; ++j) atomicAdd(&ap[j], acc[i][j]);
    }
}

// ---------------- Plan A (only if ws fits full f32 ew) ----------------
__global__ __launch_bounds__(256) void k_ew(const float* __restrict__ hid,
                                            const float* __restrict__ w2,
                                            const float* __restrict__ b2,
                                            float* __restrict__ ew, int E){
    __shared__ float As[64][64];
    __shared__ float Bs[64][65];
    int brow = blockIdx.x, bcol = blockIdx.y;
    int tid = threadIdx.x;
    int tx = tid & 15, ty = tid >> 4;
    int row0 = brow*64;
    for (int i = tid; i < 64*64; i += 256){
        int m = i >> 6, k = i & 63;
        int e = row0 + m;
        As[m][k] = (e < E) ? hid[(size_t)e*64 + k] : 0.f;
    }
    for (int i = tid; i < 64*64; i += 256){
        int j = i >> 6, k = i & 63;
        Bs[k][j] = w2[((size_t)(bcol*64 + j))*64 + k];
    }
    __syncthreads();
    float acc[4][4] = {{0.f}};
#pragma unroll 8
    for (int k = 0; k < 64; ++k){
        float a0 = As[ty*4+0][k], a1 = As[ty*4+1][k], a2 = As[ty*4+2][k], a3 = As[ty*4+3][k];
        float b0 = Bs[k][tx*4+0], b1v = Bs[k][tx*4+1], b2v = Bs[k][tx*4+2], b3v = Bs[k][tx*4+3];
        acc[0][0] += a0*b0; acc[0][1] += a0*b1v; acc[0][2] += a0*b2v; acc[0][3] += a0*b3v;
        acc[1][0] += a1*b0; acc[1][1] += a1*b1v; acc[1][2] += a1*b2v; acc[1][3] += a1*b3v;
        acc[2][0] += a2*b0; acc[2][1] += a2*b1v; acc[2][2] += a2*b2v; acc[2][3] += a2*b3v;
        acc[3][0] += a3*b0; acc[3][1] += a3*b1v; acc[3][2] += a3*b2v; acc[3][3] += a3*b3v;
    }
#pragma unroll
    for (int i = 0; i < 4; ++i){
        int e = row0 + ty*4 + i;
        if (e >= E) continue;
        size_t base = (size_t)e*4096 + bcol*64 + tx*4;
        int cb = bcol*64 + tx*4;
#pragma unroll
        for (int j = 0; j < 4; ++j) ew[base + j] = acc[i][j] + b2[cb + j];
    }
}

__global__ __launch_bounds__(256) void k_msg(const float* __restrict__ out,
                                             const float* __restrict__ ew,
                                             const int* __restrict__ ei,
                                             float* __restrict__ agg, int E){
    int gw = (blockIdx.x*blockDim.x + threadIdx.x) >> 6;
    int o = threadIdx.x & 63;
    if (gw >= E) return;
    int src = ei[gw], tgt = ei[E + gw];
    float srcv = out[(size_t)src*64 + o];
    const float* ewr = ew + (size_t)gw*4096;
    float acc = 0.f;
#pragma unroll
    for (int d = 0; d < 64; d += 4){
        float s0 = __shfl(srcv, d,   64);
        float s1 = __shfl(srcv, d+1, 64);
        float s2 = __shfl(srcv, d+2, 64);
        float s3 = __shfl(srcv, d+3, 64);
        acc += s0*ewr[d*64+o] + s1*ewr[(d+1)*64+o] + s2*ewr[(d+2)*64+o] + s3*ewr[(d+3)*64+o];
    }
    atomicAdd(&agg[(size_t)tgt*64 + o], acc);
}

// ---------------- conv + GRU node update ----------------
__global__ __launch_bounds__(256) void k_node(float* __restrict__ out, float* __restrict__ h,
                                              const float* __restrict__ agg,
                                              const float* __restrict__ invdeg,
                                              const float* __restrict__ rootw,
                                              const float* __restrict__ convb,
                                              const float* __restrict__ wihT,
                                              const float* __restrict__ whhT,
                                              const float* __restrict__ bih,
                                              const float* __restrict__ bhh, int N){
    int gw = (blockIdx.x*blockDim.x + threadIdx.x) >> 6;
    int o = threadIdx.x & 63;
    if (gw >= N) return;
    size_t base = (size_t)gw*64;
    float outv = out[base + o];
    float hv   = h[base + o];
    float conv = agg[base + o]*invdeg[gw] + convb[o];
#pragma unroll 4
    for (int d = 0; d < 64; ++d) conv += __shfl(outv, d, 64) * rootw[d*64 + o];
    float m = leaky(conv);
    float gir = bih[o], giz = bih[64+o], gin = bih[128+o];
    float ghr = bhh[o], ghz = bhh[64+o], ghn = bhh[128+o];
#pragma unroll 4
    for (int d = 0; d < 64; ++d){
        float md = __shfl(m, d, 64);
        float hd = __shfl(hv, d, 64);
        const float* wi = wihT + d*192;
        const float* wh = whhT + d*192;
        gir += md*wi[o]; giz += md*wi[64+o]; gin += md*wi[128+o];
        ghr += hd*wh[o]; ghz += hd*wh[64+o]; ghn += hd*wh[128+o];
    }
    float r = sigm(gir + ghr), z = sigm(giz + ghz);
    float nn = tanhf(gin + r*ghn);
    float hnew = (1.f - z)*nn + z*hv;
    h[base + o] = hnew;
    out[base + o] = hnew;
}

// ---------------- Set2Set (1 step, zero init) + readout ----------------
__global__ void k_q(const float* __restrict__ bih, const float* __restrict__ bhh,
                    float* __restrict__ q){
    int j = threadIdx.x;
    if (j >= 64) return;
    float gi = bih[j]       + bhh[j];
    float gg = bih[128+j]   + bhh[128+j];
    float go = bih[192+j]   + bhh[192+j];
    float c = sigm(gi)*tanhf(gg);
    q[j] = sigm(go)*tanhf(c);
}

__device__ __forceinline__ unsigned fkey(float f){
    unsigned u = __float_as_uint(f);
    return (u >> 31) ? ~u : (u | 0x80000000u);
}

__global__ void k_edot(const float* __restrict__ out, const float* __restrict__ q,
                       const int* __restrict__ batch, float* __restrict__ ebuf,
                       unsigned* __restrict__ emaxk, int N){
    int gw = (blockIdx.x*blockDim.x + threadIdx.x) >> 6;
    int d = threadIdx.x & 63;
    if (gw >= N) return;
    float v = out[(size_t)gw*64 + d] * q[d];
#pragma unroll
    for (int s = 32; s; s >>= 1) v += __shfl_xor(v, s, 64);
    if (d == 0){
        ebuf[gw] = v;
        atomicMax(&emaxk[batch[gw]], fkey(v));
    }
}

__global__ void k_ex(float* __restrict__ ebuf, const unsigned* __restrict__ emaxk,
                     const int* __restrict__ batch, float* __restrict__ denom, int N){
    int n = blockIdx.x*blockDim.x + threadIdx.x;
    if (n >= N) return;
    int b = batch[n];
    unsigned k = emaxk[b];
    float em = (k == 0u) ? 0.f
             : ((k >> 31) ? __uint_as_float(k ^ 0x80000000u) : __uint_as_float(~k));
    float ex = expf(ebuf[n] - em);
    ebuf[n] = ex;
    atomicAdd(&denom[b], ex);
}

__global__ void k_rr(const float* __restrict__ out, const float* __restrict__ ebuf,
                     const float* __restrict__ denom, const int* __restrict__ batch,
                     float* __restrict__ rr, int N){
    int gw = (blockIdx.x*blockDim.x + threadIdx.x) >> 6;
    int o = threadIdx.x & 63;
    if (gw >= N) return;
    int b = batch[gw];
    float a = ebuf[gw] / fmaxf(denom[b], 1e-16f);
    atomicAdd(&rr[(size_t)b*64 + o], a * out[(size_t)gw*64 + o]);
}

__global__ void k_out(const float* __restrict__ q, const float* __restrict__ rr,
                      const float* __restrict__ lw, const float* __restrict__ lb,
                      float* __restrict__ dout){
    int i = blockIdx.x*blockDim.x + threadIdx.x;
    if (i >= NGRAPH*ODIM) return;
    int b = i / ODIM, j = i % ODIM;
    const float* w = lw + j*128;
    float acc = lb[j];
#pragma unroll 8
    for (int d = 0; d < 64; ++d) acc += w[d]*q[d];
    const float* rb = rr + (size_t)b*64;
#pragma unroll 8
    for (int d = 0; d < 64; ++d) acc += w[64+d]*rb[d];
    dout[i] = acc;
}

// ---------------- launch ----------------
extern "C" void kernel_launch(void* const* d_in, const int* in_sizes, int n_in,
                              void* d_out, int out_size, void* d_ws, size_t ws_size,
                              hipStream_t stream){
    const float* x     = (const float*)d_in[0];
    const float* ea    = (const float*)d_in[1];
    const int*   ei    = (const int*)  d_in[2];
    const int*   batch = (const int*)  d_in[3];
    const float* lin0w = (const float*)d_in[4];
    const float* lin0b = (const float*)d_in[5];
    const float* w1    = (const float*)d_in[6];
    const float* b1    = (const float*)d_in[7];
    const float* w2    = (const float*)d_in[8];
    const float* b2    = (const float*)d_in[9];
    const float* rootw = (const float*)d_in[10];
    const float* convb = (const float*)d_in[11];
    const float* gwih  = (const float*)d_in[12];
    const float* gwhh  = (const float*)d_in[13];
    const float* gbih  = (const float*)d_in[14];
    const float* gbhh  = (const float*)d_in[15];
    const float* lsbih = (const float*)d_in[18];
    const float* lsbhh = (const float*)d_in[19];
    const float* loutw = (const float*)d_in[20];
    const float* loutb = (const float*)d_in[21];

    int N = in_sizes[0] / NFEAT;
    int E = in_sizes[1] / EFEAT;

    char* p = (char*)d_ws;
    size_t off = 0;
    auto carve = [&](size_t bytes) -> void* {
        void* r = p + off;
        off += (bytes + 255) & ~(size_t)255;
        return r;
    };
    float*    hid    = (float*)   carve((size_t)E*64*4);
    float*    outb   = (float*)   carve((size_t)N*64*4);
    float*    hb     = (float*)   carve((size_t)N*64*4);
    float*    agg    = (float*)   carve((size_t)N*64*4);
    float*    invdeg = (float*)   carve((size_t)N*4);
    float*    qv     = (float*)   carve(64*4);
    float*    ebuf   = (float*)   carve((size_t)N*4);
    unsigned* emaxk  = (unsigned*)carve(NGRAPH*4);
    float*    denom  = (float*)   carve(NGRAPH*4);
    float*    rr     = (float*)   carve((size_t)NGRAPH*64*4);
    float*    wihT   = (float*)   carve(192*64*4);
    float*    whhT   = (float*)   carve(192*64*4);
    float*    wperm  = (float*)   carve((size_t)64*64*64*4);
    float*    ew     = (float*)(p + off);
    size_t need_ew = off + (size_t)E*4096*4;
    bool use_ew = (ws_size >= need_ew);

    hipMemsetAsync(invdeg, 0, (size_t)N*4, stream);
    hipMemsetAsync(emaxk, 0, NGRAPH*4, stream);
    hipMemsetAsync(denom, 0, NGRAPH*4, stream);
    hipMemsetAsync(rr,    0, (size_t)NGRAPH*64*4, stream);

    k_transpose<<<(2*192*64 + 255)/256, 256, 0, stream>>>(gwih, gwhh, wihT, whhT);
    k_wperm<<<(64*64*64 + 255)/256, 256, 0, stream>>>(w2, wperm);
    k_hid<<<((size_t)E*64 + 255)/256, 256, 0, stream>>>(ea, w1, b1, hid, E);
    k_deg<<<(E + 255)/256, 256, 0, stream>>>(ei, invdeg, E);
    k_invdeg<<<(N + 255)/256, 256, 0, stream>>>(invdeg, N);
    k_lin0<<<((size_t)N*64 + 255)/256, 256, 0, stream>>>(x, lin0w, lin0b, outb, hb, N);

    if (use_ew){
        dim3 g((E + 63)/64, 64);
        k_ew<<<g, 256, 0, stream>>>(hid, w2, b2, ew, E);
    }

    int msg_grid  = ((size_t)E*64 + 255)/256;
    int node_grid = ((size_t)N*64 + 255)/256;
    int fmsg_grid = (E + 63)/64;
    for (int it = 0; it < 6; ++it){
        hipMemsetAsync(agg, 0, (size_t)N*64*4, stream);
        if (use_ew)
            k_msg<<<msg_grid, 256, 0, stream>>>(outb, ew, ei, agg, E);
        else
            k_fmsg<<<fmsg_grid, 256, 0, stream>>>(outb, hid, wperm, b2, ei, agg, E);
        k_node<<<node_grid, 256, 0, stream>>>(outb, hb, agg, invdeg, rootw, convb,
                                              wihT, whhT, gbih, gbhh, N);
    }

    k_q<<<1, 64, 0, stream>>>(lsbih, lsbhh, qv);
    k_edot<<<node_grid, 256, 0, stream>>>(outb, qv, batch, ebuf, emaxk, N);
    k_ex<<<(N + 255)/256, 256, 0, stream>>>(ebuf, emaxk, batch, denom, N);
    k_rr<<<node_grid, 256, 0, stream>>>(outb, ebuf, denom, batch, rr, N);
    k_out<<<(NGRAPH*ODIM + 255)/256, 256, 0, stream>>>(qv, rr, loutw, loutb, (float*)d_out);
}

// Round 3
// 855.586 us; speedup vs baseline: 32.8688x; 3.3908x over previous
//
#include <hip/hip_runtime.h>
#include <math.h>

#define DIM 64
#define NFEAT 14
#define EFEAT 4
#define ODIM 16
#define NGRAPH 512
#define NEG 0.01f

typedef _Float16 f16;
typedef _Float16 f16x8 __attribute__((ext_vector_type(8)));
typedef float f32x4 __attribute__((ext_vector_type(4)));

#define MFMA(a,b,c) __builtin_amdgcn_mfma_f32_16x16x32_f16(a,b,c,0,0,0)

__device__ __forceinline__ float leaky(float v){ return v >= 0.f ? v : NEG*v; }
__device__ __forceinline__ float sigm(float v){ return 1.f/(1.f+expf(-v)); }

// ---------- generic B-fragment packer ----------
// dst fragment layout (consumed as f16x8): flat f16 idx = ((CT*2+s)*64 + l)*8 + j
// value = B[k][c] with k=(l>>4)*8+32*s+j, c=CT*16+(l&15)
// transB=0: B[k][c] = src[c*64+k]   (src is [C][64] row-major, contraction over its 2nd dim)
// transB=1: B[k][c] = src[k*NC+c]   (src is [64][NC] row-major)
__global__ void k_pack(const float* __restrict__ src, f16* __restrict__ dst, int NC, int transB){
    int i = blockIdx.x*blockDim.x + threadIdx.x;
    if (i >= NC*64) return;
    int j = i & 7, l = (i >> 3) & 63, s = (i >> 9) & 1, CT = i >> 10;
    int k = ((l >> 4) << 3) + 32*s + j;
    int c = CT*16 + (l & 15);
    float v = transB ? src[(size_t)k*NC + c] : src[(size_t)c*64 + k];
    dst[i] = (f16)v;
}

// ---------- small prep ----------
__global__ void k_hid(const float* __restrict__ ea, const float* __restrict__ w1,
                      const float* __restrict__ b1, f16* __restrict__ hid16, int E){
    int i = blockIdx.x*blockDim.x + threadIdx.x;
    if (i >= E*DIM) return;
    int e = i >> 6, k = i & 63;
    const float* a = ea + (size_t)e*EFEAT;
    const float* w = w1 + k*EFEAT;
    float v = b1[k] + a[0]*w[0] + a[1]*w[1] + a[2]*w[2] + a[3]*w[3];
    hid16[i] = (f16)leaky(v);
}

__global__ void k_deg(const int* __restrict__ ei, float* __restrict__ deg, int E){
    int e = blockIdx.x*blockDim.x + threadIdx.x;
    if (e < E) atomicAdd(&deg[ei[E + e]], 1.0f);
}

__global__ void k_invdeg(float* __restrict__ deg, int N){
    int i = blockIdx.x*blockDim.x + threadIdx.x;
    if (i < N) deg[i] = 1.0f / fmaxf(deg[i], 1.0f);
}

__global__ void k_lin0(const float* __restrict__ x, const float* __restrict__ w,
                       const float* __restrict__ b, float* __restrict__ hf,
                       f16* __restrict__ out16, int N){
    int i = blockIdx.x*blockDim.x + threadIdx.x;
    if (i >= N*DIM) return;
    int n = i >> 6, o = i & 63;
    const float* xr = x + (size_t)n*NFEAT;
    const float* wr = w + o*NFEAT;
    float v = b[o];
#pragma unroll
    for (int f = 0; f < NFEAT; ++f) v += xr[f]*wr[f];
    v = leaky(v);
    hf[i] = v; out16[i] = (f16)v;
}

// ---------- per-node bias GEMM: nb = out16 @ b2  (N x 64) ----------
__global__ __launch_bounds__(256) void k_nbias(const f16x8* __restrict__ out16v,
                                               const f16x8* __restrict__ b2f,
                                               float* __restrict__ nb, int N){
    int n0 = blockIdx.x*64;
    int tid = threadIdx.x, w = tid >> 6, l = tid & 63, li = l & 15, lh = l >> 4;
    int ar = n0 + 16*w + li;
    f16x8 a0{}, a1{};
    if (ar < N){ a0 = out16v[(size_t)ar*8 + lh]; a1 = out16v[(size_t)ar*8 + lh + 4]; }
    f32x4 z = {0.f,0.f,0.f,0.f};
#pragma unroll
    for (int ct = 0; ct < 4; ++ct){
        f32x4 p = MFMA(a0, b2f[(ct*2+0)*64 + l], z);
        p = MFMA(a1, b2f[(ct*2+1)*64 + l], p);
#pragma unroll
        for (int reg = 0; reg < 4; ++reg){
            int n = n0 + 16*w + lh*4 + reg;
            if (n < N) nb[(size_t)n*64 + ct*16 + li] = p[reg];
        }
    }
}

// ---------- fused message: MFMA over (hid @ W2p_d), f32-scale by out[src,d], scatter ----------
__global__ __launch_bounds__(256) void k_fmsg(const float* __restrict__ hf,
                                              const f16x8* __restrict__ hid16v,
                                              const f16x8* __restrict__ wpf,
                                              const float* __restrict__ nb,
                                              const int* __restrict__ ei,
                                              float* __restrict__ agg, int E){
    __shared__ float Os[64][65];
    __shared__ float Msg[64][65];
    __shared__ int ssrc[64];
    __shared__ int stgt[64];
    int tid = threadIdx.x;
    int e0 = blockIdx.x*64;
    if (tid < 64){
        int e = e0 + tid;
        ssrc[tid] = (e < E) ? ei[e] : -1;
        stgt[tid] = (e < E) ? ei[E + e] : -1;
    }
    for (int i = tid; i < 4096; i += 256) Msg[i >> 6][i & 63] = 0.f;
    __syncthreads();
    for (int i = tid; i < 4096; i += 256){
        int e = i >> 6, d = i & 63;
        int s = ssrc[e];
        Os[e][d] = (s >= 0) ? hf[(size_t)s*64 + d] : 0.f;
    }

    int w = tid >> 6, l = tid & 63, li = l & 15, lh = l >> 4;
    f16x8 a[4][2];
#pragma unroll
    for (int rt = 0; rt < 4; ++rt){
        int e = e0 + rt*16 + li;
        if (e < E){
            a[rt][0] = hid16v[(size_t)e*8 + lh];
            a[rt][1] = hid16v[(size_t)e*8 + lh + 4];
        } else {
            a[rt][0] = f16x8{}; a[rt][1] = f16x8{};
        }
    }
    __syncthreads();

    float acc[4][4][4] = {};
    f32x4 z = {0.f,0.f,0.f,0.f};
    // wave w owns d in [16w, 16w+16)
    for (int dd = 0; dd < 16; ++dd){
        int d = w*16 + dd;
        f16x8 b[4][2];
#pragma unroll
        for (int ct = 0; ct < 4; ++ct){
            b[ct][0] = wpf[((size_t)d*8 + ct*2 + 0)*64 + l];
            b[ct][1] = wpf[((size_t)d*8 + ct*2 + 1)*64 + l];
        }
        float osv[4][4];
#pragma unroll
        for (int rt = 0; rt < 4; ++rt)
#pragma unroll
            for (int reg = 0; reg < 4; ++reg)
                osv[rt][reg] = Os[rt*16 + lh*4 + reg][d];
#pragma unroll
        for (int rt = 0; rt < 4; ++rt){
#pragma unroll
            for (int ct = 0; ct < 4; ++ct){
                f32x4 p = MFMA(a[rt][0], b[ct][0], z);
                p = MFMA(a[rt][1], b[ct][1], p);
#pragma unroll
                for (int reg = 0; reg < 4; ++reg)
                    acc[rt][ct][reg] += osv[rt][reg]*p[reg];
            }
        }
    }

    // combine wave partials in LDS
#pragma unroll
    for (int rt = 0; rt < 4; ++rt)
#pragma unroll
        for (int ct = 0; ct < 4; ++ct)
#pragma unroll
            for (int reg = 0; reg < 4; ++reg)
                atomicAdd(&Msg[rt*16 + lh*4 + reg][ct*16 + li], acc[rt][ct][reg]);
    __syncthreads();

    // global scatter (+ per-src-node bias term)
    for (int i = tid; i < 4096; i += 256){
        int row = i >> 6, col = i & 63;
        int t = stgt[row];
        if (t >= 0){
            float v = Msg[row][col] + nb[(size_t)ssrc[row]*64 + col];
            atomicAdd(&agg[(size_t)t*64 + col], v);
        }
    }
}

// ---------- conv + GRU node update (MFMA) ----------
__global__ __launch_bounds__(256) void k_node(float* __restrict__ hf,
                                              f16* __restrict__ out16,
                                              const f16x8* __restrict__ out16v,
                                              const float* __restrict__ agg,
                                              const float* __restrict__ invdeg,
                                              const float* __restrict__ convb,
                                              const f16x8* __restrict__ wrf,
                                              const f16x8* __restrict__ wihf,
                                              const f16x8* __restrict__ whhf,
                                              const float* __restrict__ bih,
                                              const float* __restrict__ bhh, int N){
    __shared__ f16 Ms[64][72];
    int n0 = blockIdx.x*64;
    int tid = threadIdx.x, w = tid >> 6, l = tid & 63, li = l & 15, lh = l >> 4;
    f32x4 z = {0.f,0.f,0.f,0.f};

    int ar = n0 + 16*w + li;
    f16x8 a0{}, a1{};
    if (ar < N){ a0 = out16v[(size_t)ar*8 + lh]; a1 = out16v[(size_t)ar*8 + lh + 4]; }

    int nrow[4]; float invd[4];
#pragma unroll
    for (int reg = 0; reg < 4; ++reg){
        nrow[reg] = n0 + 16*w + lh*4 + reg;
        invd[reg] = (nrow[reg] < N) ? invdeg[nrow[reg]] : 0.f;
    }

    // phase 1: m = leaky(agg*invdeg + out@rootw + convb)
#pragma unroll
    for (int ct = 0; ct < 4; ++ct){
        f32x4 p = MFMA(a0, wrf[(ct*2+0)*64 + l], z);
        p = MFMA(a1, wrf[(ct*2+1)*64 + l], p);
        int col = ct*16 + li;
        float cb = convb[col];
#pragma unroll
        for (int reg = 0; reg < 4; ++reg){
            int n = nrow[reg];
            float m = 0.f;
            if (n < N) m = leaky(p[reg] + agg[(size_t)n*64 + col]*invd[reg] + cb);
            Ms[16*w + lh*4 + reg][col] = (f16)m;
        }
    }
    __syncthreads();

    // phase 2: GRU gates
    f16x8 am0 = *(const f16x8*)&Ms[16*w + li][lh*8];
    f16x8 am1 = *(const f16x8*)&Ms[16*w + li][lh*8 + 32];

#pragma unroll
    for (int ctq = 0; ctq < 4; ++ctq){
        int col = ctq*16 + li;
        f32x4 pir = MFMA(am0, wihf[((ctq+0)*2+0)*64 + l], z);
        pir = MFMA(am1, wihf[((ctq+0)*2+1)*64 + l], pir);
        f32x4 piz = MFMA(am0, wihf[((ctq+4)*2+0)*64 + l], z);
        piz = MFMA(am1, wihf[((ctq+4)*2+1)*64 + l], piz);
        f32x4 pin = MFMA(am0, wihf[((ctq+8)*2+0)*64 + l], z);
        pin = MFMA(am1, wihf[((ctq+8)*2+1)*64 + l], pin);
        f32x4 phr = MFMA(a0, whhf[((ctq+0)*2+0)*64 + l], z);
        phr = MFMA(a1, whhf[((ctq+0)*2+1)*64 + l], phr);
        f32x4 phz = MFMA(a0, whhf[((ctq+4)*2+0)*64 + l], z);
        phz = MFMA(a1, whhf[((ctq+4)*2+1)*64 + l], phz);
        f32x4 phn = MFMA(a0, whhf[((ctq+8)*2+0)*64 + l], z);
        phn = MFMA(a1, whhf[((ctq+8)*2+1)*64 + l], phn);
        float bir = bih[col], biz = bih[64+col], bin = bih[128+col];
        float bhr = bhh[col], bhz = bhh[64+col], bhn = bhh[128+col];
#pragma unroll
        for (int reg = 0; reg < 4; ++reg){
            int n = nrow[reg];
            if (n >= N) continue;
            float hv = hf[(size_t)n*64 + col];
            float r  = sigm(pir[reg] + bir + phr[reg] + bhr);
            float zz = sigm(piz[reg] + biz + phz[reg] + bhz);
            float nn = tanhf(pin[reg] + bin + r*(phn[reg] + bhn));
            float hnew = (1.f - zz)*nn + zz*hv;
            hf[(size_t)n*64 + col] = hnew;
            out16[(size_t)n*64 + col] = (f16)hnew;
        }
    }
}

// ---------- Set2Set (1 step, zero init) + readout ----------
__global__ void k_q(const float* __restrict__ bih, const float* __restrict__ bhh,
                    float* __restrict__ q){
    int j = threadIdx.x;
    if (j >= 64) return;
    float gi = bih[j]       + bhh[j];
    float gg = bih[128+j]   + bhh[128+j];
    float go = bih[192+j]   + bhh[192+j];
    float c = sigm(gi)*tanhf(gg);
    q[j] = sigm(go)*tanhf(c);
}

__device__ __forceinline__ unsigned fkey(float f){
    unsigned u = __float_as_uint(f);
    return (u >> 31) ? ~u : (u | 0x80000000u);
}

__global__ void k_edot(const float* __restrict__ out, const float* __restrict__ q,
                       const int* __restrict__ batch, float* __restrict__ ebuf,
                       unsigned* __restrict__ emaxk, int N){
    int gw = (blockIdx.x*blockDim.x + threadIdx.x) >> 6;
    int d = threadIdx.x & 63;
    if (gw >= N) return;
    float v = out[(size_t)gw*64 + d] * q[d];
#pragma unroll
    for (int s = 32; s; s >>= 1) v += __shfl_xor(v, s, 64);
    if (d == 0){
        ebuf[gw] = v;
        atomicMax(&emaxk[batch[gw]], fkey(v));
    }
}

__global__ void k_ex(float* __restrict__ ebuf, const unsigned* __restrict__ emaxk,
                     const int* __restrict__ batch, float* __restrict__ denom, int N){
    int n = blockIdx.x*blockDim.x + threadIdx.x;
    if (n >= N) return;
    int b = batch[n];
    unsigned k = emaxk[b];
    float em = (k == 0u) ? 0.f
             : ((k >> 31) ? __uint_as_float(k ^ 0x80000000u) : __uint_as_float(~k));
    float ex = expf(ebuf[n] - em);
    ebuf[n] = ex;
    atomicAdd(&denom[b], ex);
}

__global__ void k_rr(const float* __restrict__ out, const float* __restrict__ ebuf,
                     const float* __restrict__ denom, const int* __restrict__ batch,
                     float* __restrict__ rr, int N){
    int gw = (blockIdx.x*blockDim.x + threadIdx.x) >> 6;
    int o = threadIdx.x & 63;
    if (gw >= N) return;
    int b = batch[gw];
    float a = ebuf[gw] / fmaxf(denom[b], 1e-16f);
    atomicAdd(&rr[(size_t)b*64 + o], a * out[(size_t)gw*64 + o]);
}

__global__ void k_out(const float* __restrict__ q, const float* __restrict__ rr,
                      const float* __restrict__ lw, const float* __restrict__ lb,
                      float* __restrict__ dout){
    int i = blockIdx.x*blockDim.x + threadIdx.x;
    if (i >= NGRAPH*ODIM) return;
    int b = i / ODIM, j = i % ODIM;
    const float* w = lw + j*128;
    float acc = lb[j];
#pragma unroll 8
    for (int d = 0; d < 64; ++d) acc += w[d]*q[d];
    const float* rb = rr + (size_t)b*64;
#pragma unroll 8
    for (int d = 0; d < 64; ++d) acc += w[64+d]*rb[d];
    dout[i] = acc;
}

// ---------- launch ----------
extern "C" void kernel_launch(void* const* d_in, const int* in_sizes, int n_in,
                              void* d_out, int out_size, void* d_ws, size_t ws_size,
                              hipStream_t stream){
    const float* x     = (const float*)d_in[0];
    const float* ea    = (const float*)d_in[1];
    const int*   ei    = (const int*)  d_in[2];
    const int*   batch = (const int*)  d_in[3];
    const float* lin0w = (const float*)d_in[4];
    const float* lin0b = (const float*)d_in[5];
    const float* w1    = (const float*)d_in[6];
    const float* b1    = (const float*)d_in[7];
    const float* w2    = (const float*)d_in[8];
    const float* b2    = (const float*)d_in[9];
    const float* rootw = (const float*)d_in[10];
    const float* convb = (const float*)d_in[11];
    const float* gwih  = (const float*)d_in[12];
    const float* gwhh  = (const float*)d_in[13];
    const float* gbih  = (const float*)d_in[14];
    const float* gbhh  = (const float*)d_in[15];
    const float* lsbih = (const float*)d_in[18];
    const float* lsbhh = (const float*)d_in[19];
    const float* loutw = (const float*)d_in[20];
    const float* loutb = (const float*)d_in[21];

    int N = in_sizes[0] / NFEAT;
    int E = in_sizes[1] / EFEAT;

    char* p = (char*)d_ws;
    size_t off = 0;
    auto carve = [&](size_t bytes) -> void* {
        void* r = p + off;
        off += (bytes + 255) & ~(size_t)255;
        return r;
    };
    f16*      hid16  = (f16*)     carve((size_t)E*64*2);
    float*    hf     = (float*)   carve((size_t)N*64*4);   // out == h (identical)
    f16*      out16  = (f16*)     carve((size_t)N*64*2);
    float*    agg    = (float*)   carve((size_t)N*64*4);
    float*    nb     = (float*)   carve((size_t)N*64*4);
    float*    invdeg = (float*)   carve((size_t)N*4);
    float*    qv     = (float*)   carve(64*4);
    float*    ebuf   = (float*)   carve((size_t)N*4);
    unsigned* emaxk  = (unsigned*)carve(NGRAPH*4);
    float*    denom  = (float*)   carve(NGRAPH*4);
    float*    rr     = (float*)   carve((size_t)NGRAPH*64*4);
    f16*      wpf    = (f16*)     carve((size_t)4096*64*2);
    f16*      wrf    = (f16*)     carve(64*64*2);
    f16*      b2f    = (f16*)     carve(64*64*2);
    f16*      wihf   = (f16*)     carve(192*64*2);
    f16*      whhf   = (f16*)     carve(192*64*2);

    hipMemsetAsync(invdeg, 0, (size_t)N*4, stream);
    hipMemsetAsync(emaxk, 0, NGRAPH*4, stream);
    hipMemsetAsync(denom, 0, NGRAPH*4, stream);
    hipMemsetAsync(rr,    0, (size_t)NGRAPH*64*4, stream);

    // weight fragment packs
    k_pack<<<(4096*64 + 255)/256, 256, 0, stream>>>(w2,    wpf,  4096, 0);
    k_pack<<<(64*64   + 255)/256, 256, 0, stream>>>(rootw, wrf,  64,   1);
    k_pack<<<(64*64   + 255)/256, 256, 0, stream>>>(b2,    b2f,  64,   1);
    k_pack<<<(192*64  + 255)/256, 256, 0, stream>>>(gwih,  wihf, 192,  0);
    k_pack<<<(192*64  + 255)/256, 256, 0, stream>>>(gwhh,  whhf, 192,  0);

    k_hid<<<((size_t)E*64 + 255)/256, 256, 0, stream>>>(ea, w1, b1, hid16, E);
    k_deg<<<(E + 255)/256, 256, 0, stream>>>(ei, invdeg, E);
    k_invdeg<<<(N + 255)/256, 256, 0, stream>>>(invdeg, N);
    k_lin0<<<((size_t)N*64 + 255)/256, 256, 0, stream>>>(x, lin0w, lin0b, hf, out16, N);

    int eb = (E + 63)/64;
    int nbk = (N + 63)/64;
    int node_grid = ((size_t)N*64 + 255)/256;
    for (int it = 0; it < 6; ++it){
        hipMemsetAsync(agg, 0, (size_t)N*64*4, stream);
        k_nbias<<<nbk, 256, 0, stream>>>((const f16x8*)out16, (const f16x8*)b2f, nb, N);
        k_fmsg<<<eb, 256, 0, stream>>>(hf, (const f16x8*)hid16, (const f16x8*)wpf,
                                       nb, ei, agg, E);
        k_node<<<nbk, 256, 0, stream>>>(hf, out16, (const f16x8*)out16, agg, invdeg,
                                        convb, (const f16x8*)wrf, (const f16x8*)wihf,
                                        (const f16x8*)whhf, gbih, gbhh, N);
    }

    k_q<<<1, 64, 0, stream>>>(lsbih, lsbhh, qv);
    k_edot<<<node_grid, 256, 0, stream>>>(hf, qv, batch, ebuf, emaxk, N);
    k_ex<<<(N + 255)/256, 256, 0, stream>>>(ebuf, emaxk, batch, denom, N);
    k_rr<<<node_grid, 256, 0, stream>>>(hf, ebuf, denom, batch, rr, N);
    k_out<<<(NGRAPH*ODIM + 255)/256, 256, 0, stream>>>(qv, rr, loutw, loutb, (float*)d_out);
}

// Round 4
// 588.978 us; speedup vs baseline: 47.7473x; 1.4527x over previous
//
#include <hip/hip_runtime.h>
#include <math.h>

#define DIM 64
#define NFEAT 14
#define EFEAT 4
#define ODIM 16
#define NGRAPH 512
#define NEG 0.01f
#define EBLK 128

typedef _Float16 f16;
typedef _Float16 f16x8 __attribute__((ext_vector_type(8)));
typedef float f32x4 __attribute__((ext_vector_type(4)));

#define MFMA(a,b,c) __builtin_amdgcn_mfma_f32_16x16x32_f16(a,b,c,0,0,0)

__device__ __forceinline__ float leaky(float v){ return v >= 0.f ? v : NEG*v; }
__device__ __forceinline__ float sigm(float v){ return 1.f/(1.f+expf(-v)); }

// ---------- generic B-fragment packer ----------
// dst fragment layout (consumed as f16x8): flat f16 idx = ((CT*2+s)*64 + l)*8 + j
// value = B[k][c] with k=(l>>4)*8+32*s+j, c=CT*16+(l&15)
// transB=0: B[k][c] = src[c*64+k]   transB=1: B[k][c] = src[k*NC+c]
__global__ void k_pack(const float* __restrict__ src, f16* __restrict__ dst, int NC, int transB){
    int i = blockIdx.x*blockDim.x + threadIdx.x;
    if (i >= NC*64) return;
    int j = i & 7, l = (i >> 3) & 63, s = (i >> 9) & 1, CT = i >> 10;
    int k = ((l >> 4) << 3) + 32*s + j;
    int c = CT*16 + (l & 15);
    float v = transB ? src[(size_t)k*NC + c] : src[(size_t)c*64 + k];
    dst[i] = (f16)v;
}

// ---------- small prep ----------
__global__ void k_hid(const float* __restrict__ ea, const float* __restrict__ w1,
                      const float* __restrict__ b1, f16* __restrict__ hid16, int E){
    int i = blockIdx.x*blockDim.x + threadIdx.x;
    if (i >= E*DIM) return;
    int e = i >> 6, k = i & 63;
    const float* a = ea + (size_t)e*EFEAT;
    const float* w = w1 + k*EFEAT;
    float v = b1[k] + a[0]*w[0] + a[1]*w[1] + a[2]*w[2] + a[3]*w[3];
    hid16[i] = (f16)leaky(v);
}

__global__ void k_deg(const int* __restrict__ ei, float* __restrict__ deg, int E){
    int e = blockIdx.x*blockDim.x + threadIdx.x;
    if (e < E) atomicAdd(&deg[ei[E + e]], 1.0f);
}

__global__ void k_invdeg(float* __restrict__ deg, int N){
    int i = blockIdx.x*blockDim.x + threadIdx.x;
    if (i < N) deg[i] = 1.0f / fmaxf(deg[i], 1.0f);
}

__global__ void k_lin0(const float* __restrict__ x, const float* __restrict__ w,
                       const float* __restrict__ b, float* __restrict__ hf,
                       f16* __restrict__ out16, int N){
    int i = blockIdx.x*blockDim.x + threadIdx.x;
    if (i >= N*DIM) return;
    int n = i >> 6, o = i & 63;
    const float* xr = x + (size_t)n*NFEAT;
    const float* wr = w + o*NFEAT;
    float v = b[o];
#pragma unroll
    for (int f = 0; f < NFEAT; ++f) v += xr[f]*wr[f];
    v = leaky(v);
    hf[i] = v; out16[i] = (f16)v;
}

// ---------- per-node bias GEMM: nb = out16 @ b2  (N x 64) ----------
__global__ __launch_bounds__(256) void k_nbias(const f16x8* __restrict__ out16v,
                                               const f16x8* __restrict__ b2f,
                                               float* __restrict__ nb, int N){
    int n0 = blockIdx.x*64;
    int tid = threadIdx.x, w = tid >> 6, l = tid & 63, li = l & 15, lh = l >> 4;
    int ar = n0 + 16*w + li;
    f16x8 a0{}, a1{};
    if (ar < N){ a0 = out16v[(size_t)ar*8 + lh]; a1 = out16v[(size_t)ar*8 + lh + 4]; }
    f32x4 z = {0.f,0.f,0.f,0.f};
#pragma unroll
    for (int ct = 0; ct < 4; ++ct){
        f32x4 p = MFMA(a0, b2f[(ct*2+0)*64 + l], z);
        p = MFMA(a1, b2f[(ct*2+1)*64 + l], p);
#pragma unroll
        for (int reg = 0; reg < 4; ++reg){
            int n = n0 + 16*w + lh*4 + reg;
            if (n < N) nb[(size_t)n*64 + ct*16 + li] = p[reg];
        }
    }
}

// ---------- fused message: LDS-staged weights, 32 rows/wave, no spill ----------
__global__ __launch_bounds__(256) void k_fmsg(const float* __restrict__ hf,
                                              const f16x8* __restrict__ hid16v,
                                              const f16x8* __restrict__ wpf,
                                              const float* __restrict__ nb,
                                              const int* __restrict__ ei,
                                              float* __restrict__ agg, int E){
    __shared__ float Os[EBLK][65];
    __shared__ f16x8 Wch[4*512];          // 4 d-slices * 8KB = 32 KB
    __shared__ int ssrc[EBLK];
    __shared__ int stgt[EBLK];
    int tid = threadIdx.x;
    int e0 = blockIdx.x*EBLK;
    if (tid < EBLK){
        int e = e0 + tid;
        ssrc[tid] = (e < E) ? ei[e] : -1;
        stgt[tid] = (e < E) ? ei[E + e] : -1;
    }
    __syncthreads();
    // stage Os: gather out[src] rows (f32)
    for (int i = tid; i < EBLK*16; i += 256){
        int row = i >> 4, c4 = i & 15;
        int s = ssrc[row];
        float4 v = make_float4(0.f,0.f,0.f,0.f);
        if (s >= 0) v = *(const float4*)(hf + (size_t)s*64 + c4*4);
        *(float4*)&Os[row][c4*4] = v;
    }

    int w = tid >> 6, l = tid & 63, li = l & 15, lh = l >> 4;
    // A-fragments: wave w owns rows [w*32, w*32+32)
    f16x8 a[2][2];
#pragma unroll
    for (int rt = 0; rt < 2; ++rt){
        int e = e0 + w*32 + rt*16 + li;
        if (e < E){
            a[rt][0] = hid16v[(size_t)e*8 + lh];
            a[rt][1] = hid16v[(size_t)e*8 + lh + 4];
        } else { a[rt][0] = f16x8{}; a[rt][1] = f16x8{}; }
    }

    float acc[2][4][4] = {};
    f32x4 z = {0.f,0.f,0.f,0.f};

    for (int g = 0; g < 16; ++g){
        __syncthreads();
        const f16x8* srcp = wpf + (size_t)g*2048;
        for (int i = tid; i < 2048; i += 256) Wch[i] = srcp[i];
        __syncthreads();
#pragma unroll
        for (int dd = 0; dd < 4; ++dd){
            int d = g*4 + dd;
            f16x8 b[4][2];
#pragma unroll
            for (int ct = 0; ct < 4; ++ct){
                b[ct][0] = Wch[dd*512 + (ct*2+0)*64 + l];
                b[ct][1] = Wch[dd*512 + (ct*2+1)*64 + l];
            }
            float osv[2][4];
#pragma unroll
            for (int rt = 0; rt < 2; ++rt)
#pragma unroll
                for (int reg = 0; reg < 4; ++reg)
                    osv[rt][reg] = Os[w*32 + rt*16 + lh*4 + reg][d];
#pragma unroll
            for (int rt = 0; rt < 2; ++rt){
#pragma unroll
                for (int ct = 0; ct < 4; ++ct){
                    f32x4 p = MFMA(a[rt][0], b[ct][0], z);
                    p = MFMA(a[rt][1], b[ct][1], p);
#pragma unroll
                    for (int reg = 0; reg < 4; ++reg)
                        acc[rt][ct][reg] += osv[rt][reg]*p[reg];
                }
            }
        }
    }

    // scatter (+ per-src-node bias term); waves own disjoint rows -> direct atomics
#pragma unroll
    for (int rt = 0; rt < 2; ++rt){
#pragma unroll
        for (int reg = 0; reg < 4; ++reg){
            int row = w*32 + rt*16 + lh*4 + reg;
            int t = stgt[row];
            if (t < 0) continue;
            int s = ssrc[row];
#pragma unroll
            for (int ct = 0; ct < 4; ++ct){
                int col = ct*16 + li;
                float v = acc[rt][ct][reg] + nb[(size_t)s*64 + col];
                atomicAdd(&agg[(size_t)t*64 + col], v);
            }
        }
    }
}

// ---------- conv + GRU node update (MFMA) ----------
__global__ __launch_bounds__(256) void k_node(float* __restrict__ hf,
                                              f16* __restrict__ out16,
                                              const f16x8* __restrict__ out16v,
                                              const float* __restrict__ agg,
                                              const float* __restrict__ invdeg,
                                              const float* __restrict__ convb,
                                              const f16x8* __restrict__ wrf,
                                              const f16x8* __restrict__ wihf,
                                              const f16x8* __restrict__ whhf,
                                              const float* __restrict__ bih,
                                              const float* __restrict__ bhh, int N){
    __shared__ f16 Ms[64][72];
    int n0 = blockIdx.x*64;
    int tid = threadIdx.x, w = tid >> 6, l = tid & 63, li = l & 15, lh = l >> 4;
    f32x4 z = {0.f,0.f,0.f,0.f};

    int ar = n0 + 16*w + li;
    f16x8 a0{}, a1{};
    if (ar < N){ a0 = out16v[(size_t)ar*8 + lh]; a1 = out16v[(size_t)ar*8 + lh + 4]; }

    int nrow[4]; float invd[4];
#pragma unroll
    for (int reg = 0; reg < 4; ++reg){
        nrow[reg] = n0 + 16*w + lh*4 + reg;
        invd[reg] = (nrow[reg] < N) ? invdeg[nrow[reg]] : 0.f;
    }

    // phase 1: m = leaky(agg*invdeg + out@rootw + convb)
#pragma unroll
    for (int ct = 0; ct < 4; ++ct){
        f32x4 p = MFMA(a0, wrf[(ct*2+0)*64 + l], z);
        p = MFMA(a1, wrf[(ct*2+1)*64 + l], p);
        int col = ct*16 + li;
        float cb = convb[col];
#pragma unroll
        for (int reg = 0; reg < 4; ++reg){
            int n = nrow[reg];
            float m = 0.f;
            if (n < N) m = leaky(p[reg] + agg[(size_t)n*64 + col]*invd[reg] + cb);
            Ms[16*w + lh*4 + reg][col] = (f16)m;
        }
    }
    __syncthreads();

    // phase 2: GRU gates
    f16x8 am0 = *(const f16x8*)&Ms[16*w + li][lh*8];
    f16x8 am1 = *(const f16x8*)&Ms[16*w + li][lh*8 + 32];

#pragma unroll
    for (int ctq = 0; ctq < 4; ++ctq){
        int col = ctq*16 + li;
        f32x4 pir = MFMA(am0, wihf[((ctq+0)*2+0)*64 + l], z);
        pir = MFMA(am1, wihf[((ctq+0)*2+1)*64 + l], pir);
        f32x4 piz = MFMA(am0, wihf[((ctq+4)*2+0)*64 + l], z);
        piz = MFMA(am1, wihf[((ctq+4)*2+1)*64 + l], piz);
        f32x4 pin = MFMA(am0, wihf[((ctq+8)*2+0)*64 + l], z);
        pin = MFMA(am1, wihf[((ctq+8)*2+1)*64 + l], pin);
        f32x4 phr = MFMA(a0, whhf[((ctq+0)*2+0)*64 + l], z);
        phr = MFMA(a1, whhf[((ctq+0)*2+1)*64 + l], phr);
        f32x4 phz = MFMA(a0, whhf[((ctq+4)*2+0)*64 + l], z);
        phz = MFMA(a1, whhf[((ctq+4)*2+1)*64 + l], phz);
        f32x4 phn = MFMA(a0, whhf[((ctq+8)*2+0)*64 + l], z);
        phn = MFMA(a1, whhf[((ctq+8)*2+1)*64 + l], phn);
        float bir = bih[col], biz = bih[64+col], bin = bih[128+col];
        float bhr = bhh[col], bhz = bhh[64+col], bhn = bhh[128+col];
#pragma unroll
        for (int reg = 0; reg < 4; ++reg){
            int n = nrow[reg];
            if (n >= N) continue;
            float hv = hf[(size_t)n*64 + col];
            float r  = sigm(pir[reg] + bir + phr[reg] + bhr);
            float zz = sigm(piz[reg] + biz + phz[reg] + bhz);
            float nn = tanhf(pin[reg] + bin + r*(phn[reg] + bhn));
            float hnew = (1.f - zz)*nn + zz*hv;
            hf[(size_t)n*64 + col] = hnew;
            out16[(size_t)n*64 + col] = (f16)hnew;
        }
    }
}

// ---------- Set2Set (1 step, zero init) + readout ----------
__global__ void k_q(const float* __restrict__ bih, const float* __restrict__ bhh,
                    float* __restrict__ q){
    int j = threadIdx.x;
    if (j >= 64) return;
    float gi = bih[j]       + bhh[j];
    float gg = bih[128+j]   + bhh[128+j];
    float go = bih[192+j]   + bhh[192+j];
    float c = sigm(gi)*tanhf(gg);
    q[j] = sigm(go)*tanhf(c);
}

__device__ __forceinline__ unsigned fkey(float f){
    unsigned u = __float_as_uint(f);
    return (u >> 31) ? ~u : (u | 0x80000000u);
}

__global__ void k_edot(const float* __restrict__ out, const float* __restrict__ q,
                       const int* __restrict__ batch, float* __restrict__ ebuf,
                       unsigned* __restrict__ emaxk, int N){
    int gw = (blockIdx.x*blockDim.x + threadIdx.x) >> 6;
    int d = threadIdx.x & 63;
    if (gw >= N) return;
    float v = out[(size_t)gw*64 + d] * q[d];
#pragma unroll
    for (int s = 32; s; s >>= 1) v += __shfl_xor(v, s, 64);
    if (d == 0){
        ebuf[gw] = v;
        atomicMax(&emaxk[batch[gw]], fkey(v));
    }
}

__global__ void k_ex(float* __restrict__ ebuf, const unsigned* __restrict__ emaxk,
                     const int* __restrict__ batch, float* __restrict__ denom, int N){
    int n = blockIdx.x*blockDim.x + threadIdx.x;
    if (n >= N) return;
    int b = batch[n];
    unsigned k = emaxk[b];
    float em = (k == 0u) ? 0.f
             : ((k >> 31) ? __uint_as_float(k ^ 0x80000000u) : __uint_as_float(~k));
    float ex = expf(ebuf[n] - em);
    ebuf[n] = ex;
    atomicAdd(&denom[b], ex);
}

__global__ void k_rr(const float* __restrict__ out, const float* __restrict__ ebuf,
                     const float* __restrict__ denom, const int* __restrict__ batch,
                     float* __restrict__ rr, int N){
    int gw = (blockIdx.x*blockDim.x + threadIdx.x) >> 6;
    int o = threadIdx.x & 63;
    if (gw >= N) return;
    int b = batch[gw];
    float a = ebuf[gw] / fmaxf(denom[b], 1e-16f);
    atomicAdd(&rr[(size_t)b*64 + o], a * out[(size_t)gw*64 + o]);
}

__global__ void k_out(const float* __restrict__ q, const float* __restrict__ rr,
                      const float* __restrict__ lw, const float* __restrict__ lb,
                      float* __restrict__ dout){
    int i = blockIdx.x*blockDim.x + threadIdx.x;
    if (i >= NGRAPH*ODIM) return;
    int b = i / ODIM, j = i % ODIM;
    const float* w = lw + j*128;
    float acc = lb[j];
#pragma unroll 8
    for (int d = 0; d < 64; ++d) acc += w[d]*q[d];
    const float* rb = rr + (size_t)b*64;
#pragma unroll 8
    for (int d = 0; d < 64; ++d) acc += w[64+d]*rb[d];
    dout[i] = acc;
}

// ---------- launch ----------
extern "C" void kernel_launch(void* const* d_in, const int* in_sizes, int n_in,
                              void* d_out, int out_size, void* d_ws, size_t ws_size,
                              hipStream_t stream){
    const float* x     = (const float*)d_in[0];
    const float* ea    = (const float*)d_in[1];
    const int*   ei    = (const int*)  d_in[2];
    const int*   batch = (const int*)  d_in[3];
    const float* lin0w = (const float*)d_in[4];
    const float* lin0b = (const float*)d_in[5];
    const float* w1    = (const float*)d_in[6];
    const float* b1    = (const float*)d_in[7];
    const float* w2    = (const float*)d_in[8];
    const float* b2    = (const float*)d_in[9];
    const float* rootw = (const float*)d_in[10];
    const float* convb = (const float*)d_in[11];
    const float* gwih  = (const float*)d_in[12];
    const float* gwhh  = (const float*)d_in[13];
    const float* gbih  = (const float*)d_in[14];
    const float* gbhh  = (const float*)d_in[15];
    const float* lsbih = (const float*)d_in[18];
    const float* lsbhh = (const float*)d_in[19];
    const float* loutw = (const float*)d_in[20];
    const float* loutb = (const float*)d_in[21];

    int N = in_sizes[0] / NFEAT;
    int E = in_sizes[1] / EFEAT;

    char* p = (char*)d_ws;
    size_t off = 0;
    auto carve = [&](size_t bytes) -> void* {
        void* r = p + off;
        off += (bytes + 255) & ~(size_t)255;
        return r;
    };
    f16*      hid16  = (f16*)     carve((size_t)E*64*2);
    float*    hf     = (float*)   carve((size_t)N*64*4);
    f16*      out16  = (f16*)     carve((size_t)N*64*2);
    float*    agg    = (float*)   carve((size_t)N*64*4);
    float*    nb     = (float*)   carve((size_t)N*64*4);
    float*    invdeg = (float*)   carve((size_t)N*4);
    float*    qv     = (float*)   carve(64*4);
    float*    ebuf   = (float*)   carve((size_t)N*4);
    unsigned* emaxk  = (unsigned*)carve(NGRAPH*4);
    float*    denom  = (float*)   carve(NGRAPH*4);
    float*    rr     = (float*)   carve((size_t)NGRAPH*64*4);
    f16*      wpf    = (f16*)     carve((size_t)4096*64*2);
    f16*      wrf    = (f16*)     carve(64*64*2);
    f16*      b2f    = (f16*)     carve(64*64*2);
    f16*      wihf   = (f16*)     carve(192*64*2);
    f16*      whhf   = (f16*)     carve(192*64*2);

    hipMemsetAsync(invdeg, 0, (size_t)N*4, stream);
    hipMemsetAsync(emaxk, 0, NGRAPH*4, stream);
    hipMemsetAsync(denom, 0, NGRAPH*4, stream);
    hipMemsetAsync(rr,    0, (size_t)NGRAPH*64*4, stream);

    k_pack<<<(4096*64 + 255)/256, 256, 0, stream>>>(w2,    wpf,  4096, 0);
    k_pack<<<(64*64   + 255)/256, 256, 0, stream>>>(rootw, wrf,  64,   1);
    k_pack<<<(64*64   + 255)/256, 256, 0, stream>>>(b2,    b2f,  64,   1);
    k_pack<<<(192*64  + 255)/256, 256, 0, stream>>>(gwih,  wihf, 192,  0);
    k_pack<<<(192*64  + 255)/256, 256, 0, stream>>>(gwhh,  whhf, 192,  0);

    k_hid<<<((size_t)E*64 + 255)/256, 256, 0, stream>>>(ea, w1, b1, hid16, E);
    k_deg<<<(E + 255)/256, 256, 0, stream>>>(ei, invdeg, E);
    k_invdeg<<<(N + 255)/256, 256, 0, stream>>>(invdeg, N);
    k_lin0<<<((size_t)N*64 + 255)/256, 256, 0, stream>>>(x, lin0w, lin0b, hf, out16, N);

    int eb  = (E + EBLK - 1)/EBLK;
    int nbk = (N + 63)/64;
    int node_grid = ((size_t)N*64 + 255)/256;
    for (int it = 0; it < 6; ++it){
        hipMemsetAsync(agg, 0, (size_t)N*64*4, stream);
        k_nbias<<<nbk, 256, 0, stream>>>((const f16x8*)out16, (const f16x8*)b2f, nb, N);
        k_fmsg<<<eb, 256, 0, stream>>>(hf, (const f16x8*)hid16, (const f16x8*)wpf,
                                       nb, ei, agg, E);
        k_node<<<nbk, 256, 0, stream>>>(hf, out16, (const f16x8*)out16, agg, invdeg,
                                        convb, (const f16x8*)wrf, (const f16x8*)wihf,
                                        (const f16x8*)whhf, gbih, gbhh, N);
    }

    k_q<<<1, 64, 0, stream>>>(lsbih, lsbhh, qv);
    k_edot<<<node_grid, 256, 0, stream>>>(hf, qv, batch, ebuf, emaxk, N);
    k_ex<<<(N + 255)/256, 256, 0, stream>>>(ebuf, emaxk, batch, denom, N);
    k_rr<<<node_grid, 256, 0, stream>>>(hf, ebuf, denom, batch, rr, N);
    k_out<<<(NGRAPH*ODIM + 255)/256, 256, 0, stream>>>(qv, rr, loutw, loutb, (float*)d_out);
}